// Round 8
// baseline (492.028 us; speedup 1.0000x reference)
//
#include <hip/hip_runtime.h>
#include <hip/hip_bf16.h>

using bf16 = __hip_bfloat16;

#define S_   2048
#define D_   1024
#define H_   16
#define HD_  64
#define TE_  16
#define ED_  512
#define DS_  2048
#define CAP_ 512

#define NEG_ -1e30f

typedef __attribute__((ext_vector_type(8))) short bf16x8;
typedef __attribute__((ext_vector_type(4))) short bf16x4;
typedef __attribute__((ext_vector_type(4))) float f32x4;
#define MFMA16(a, b, c) __builtin_amdgcn_mfma_f32_16x16x32_bf16(a, b, c, 0, 0, 0)

__device__ __forceinline__ void storeF(float* p, float v) { *p = v; }
__device__ __forceinline__ void storeF(bf16* p, float v)  { *p = __float2bfloat16(v); }
__device__ __forceinline__ short cvt1(float f) {
    bf16 h = __float2bfloat16(f);
    return *(short*)&h;
}
__device__ __forceinline__ float b2f(short s) {
    return __uint_as_float(((unsigned)(unsigned short)s) << 16);
}

// async global->LDS, 16B per lane; LDS dest = wave-uniform base + lane*16
__device__ __forceinline__ void load16(const bf16* g, short* l) {
    __builtin_amdgcn_global_load_lds(
        (const __attribute__((address_space(1))) unsigned*)g,
        (__attribute__((address_space(3))) unsigned*)l, 16, 0, 0);
}

// counted-vmcnt pipeline sync: retire all but the newest stage's loads,
// then barrier. "memory" clobber orders compiler-emitted mem ops; the
// sched_barrier pins ds_reads below the barrier (guide rule #18 pattern).
__device__ __forceinline__ void pipe_wait_vm4() {
    asm volatile("s_waitcnt vmcnt(4)" ::: "memory");
    __builtin_amdgcn_s_barrier();
    __builtin_amdgcn_sched_barrier(0);
}
__device__ __forceinline__ void pipe_wait_vm3() {
    asm volatile("s_waitcnt vmcnt(3)" ::: "memory");
    __builtin_amdgcn_s_barrier();
    __builtin_amdgcn_sched_barrier(0);
}
__device__ __forceinline__ void pipe_wait_vm0() {
    asm volatile("s_waitcnt vmcnt(0)" ::: "memory");
    __builtin_amdgcn_s_barrier();
    __builtin_amdgcn_sched_barrier(0);
}

// ---------------------------------------------------------------------------
// fp32 -> bf16 convert (vectorized, 8 elems/thread). n must be multiple of 2048.
// ---------------------------------------------------------------------------
__global__ __launch_bounds__(256) void convert_kernel(
        const float* __restrict__ src, bf16* __restrict__ dst)
{
    const size_t i = ((size_t)blockIdx.x*256 + threadIdx.x)*8;
    const float4 f0 = *(const float4*)(src + i);
    const float4 f1 = *(const float4*)(src + i + 4);
    short t8[8];
    t8[0]=cvt1(f0.x); t8[1]=cvt1(f0.y); t8[2]=cvt1(f0.z); t8[3]=cvt1(f0.w);
    t8[4]=cvt1(f1.x); t8[5]=cvt1(f1.y); t8[6]=cvt1(f1.z); t8[7]=cvt1(f1.w);
    *(bf16x8*)(dst + i) = *(bf16x8*)t8;
}

// ---------------------------------------------------------------------------
// main_keys transpose: [D][TE] fp32 -> [TE][D] fp32 (tiny, 64 KB)
// ---------------------------------------------------------------------------
__global__ __launch_bounds__(256) void mkT_kernel(
        const float* __restrict__ mk, float* __restrict__ mkT)
{
    const int idx = blockIdx.x*256 + threadIdx.x;   // 0..16383
    const int e = idx >> 10, d = idx & 1023;
    mkT[idx] = mk[d*TE_ + e];
}

// ---------------------------------------------------------------------------
// RMSNorm: fp32 in -> bf16 out (float4 loads, 4 elems/thread)
// ---------------------------------------------------------------------------
__global__ __launch_bounds__(256) void rmsnorm_kernel(
        const float* __restrict__ x, const float* __restrict__ w,
        bf16* __restrict__ out)
{
    const int t = blockIdx.x, tid = threadIdx.x;
    __shared__ float red[4];
    const float4 xv = *(const float4*)(x + (size_t)t*D_ + tid*4);
    float ss = xv.x*xv.x + xv.y*xv.y + xv.z*xv.z + xv.w*xv.w;
#pragma unroll
    for (int off = 32; off; off >>= 1) ss += __shfl_xor(ss, off, 64);
    if ((tid & 63) == 0) red[tid >> 6] = ss;
    __syncthreads();
    const float rn = rsqrtf((red[0]+red[1]+red[2]+red[3]) * (1.f/D_) + 1e-5f);
    const float4 wv = *(const float4*)(w + tid*4);
    short o[4];
    o[0] = cvt1(xv.x*rn*wv.x); o[1] = cvt1(xv.y*rn*wv.y);
    o[2] = cvt1(xv.z*rn*wv.z); o[3] = cvt1(xv.w*rn*wv.w);
    *(bf16x4*)(out + (size_t)t*D_ + tid*4) = *(bf16x4*)o;
}

// ---------------------------------------------------------------------------
// MFMA GEMM, both sides bf16. 3-buffer counted-vmcnt pipeline (T4):
// prefetch distance 2, one raw barrier/iter, vmcnt never drained to 0 in
// the main loop (only at the last iteration). 48/36 KB LDS -> 3-4 blocks/CU.
// BN = 128 (2x2 waves) or BN = 64 (4x1 waves). XCD-swizzled block order.
// C[M,N] = A[M,K](bf16) @ B[N,K]^T(bf16)
// ---------------------------------------------------------------------------
template<typename OutT, bool HAS_RES, int BN>
__global__ __launch_bounds__(256) void gemm_mfma_bb_kernel(
    const bf16* __restrict__ A, const bf16* __restrict__ B,
    OutT* __restrict__ C, const float* __restrict__ Res,
    int M, int N, int K)
{
    constexpr int MI = (BN == 128) ? 4 : 2;     // M fragments per wave
    __shared__ short As[3][128*32];
    __shared__ short Bs[3][BN*32];
    const int tid = threadIdx.x;
    const int w = tid >> 6, l = tid & 63;
    const int wm = (BN == 128) ? (w >> 1) : w;
    const int wn = (BN == 128) ? (w & 1) : 0;
    // bijective XCD swizzle over flattened grid (nwg % 8 == 0 for all launches)
    const int nwg = gridDim.x * gridDim.y;
    const int bid = blockIdx.y * gridDim.x + blockIdx.x;
    const int swz = ((nwg & 7) == 0) ? ((bid & 7) * (nwg >> 3) + (bid >> 3)) : bid;
    const int bx = swz % gridDim.x, by = swz / gridDim.x;
    const int m0 = by * 128, n0 = bx * BN;
    const int lr = l >> 2, lq = l & 3;
    const int fm = l & 15, fq = l >> 4;
    f32x4 acc[MI][4];
#pragma unroll
    for (int i = 0; i < MI; ++i)
#pragma unroll
        for (int j = 0; j < 4; ++j) acc[i][j] = (f32x4){0.f,0.f,0.f,0.f};

    const bf16* ga = A + (size_t)(m0 + w*16 + lr)*K + lq*8;
    const bf16* gb = B + (size_t)(n0 + w*16 + lr)*K + lq*8;

    auto stage = [&](int buf, int k0) {
        load16(ga + k0,                &As[buf][(w*16)*32]);
        load16(ga + k0 + (size_t)64*K, &As[buf][(64 + w*16)*32]);
        load16(gb + k0,                &Bs[buf][(w*16)*32]);
        if constexpr (BN == 128)
            load16(gb + k0 + (size_t)64*K, &Bs[buf][(64 + w*16)*32]);
    };
    const int nk = K >> 5;
    stage(0, 0);
    stage(1, 32);
    int cur = 0;
    for (int t = 0; t < nk; ++t) {
        if (t + 1 < nk) {
            if constexpr (BN == 128) pipe_wait_vm4(); else pipe_wait_vm3();
        } else {
            pipe_wait_vm0();
        }
        if (t + 2 < nk) {
            const int stg = (cur + 2 >= 3) ? cur - 1 : cur + 2;
            stage(stg, (t + 2) << 5);
        }
        bf16x8 af[MI], bfr[4];
#pragma unroll
        for (int mi = 0; mi < MI; ++mi)
            af[mi] = *(const bf16x8*)&As[cur][(wm*(MI*16) + mi*16 + fm)*32 + fq*8];
#pragma unroll
        for (int ni = 0; ni < 4; ++ni)
            bfr[ni] = *(const bf16x8*)&Bs[cur][(wn*64 + ni*16 + fm)*32 + fq*8];
#pragma unroll
        for (int mi = 0; mi < MI; ++mi)
#pragma unroll
            for (int ni = 0; ni < 4; ++ni)
                acc[mi][ni] = MFMA16(af[mi], bfr[ni], acc[mi][ni]);
        cur = (cur == 2) ? 0 : cur + 1;
    }
#pragma unroll
    for (int mi = 0; mi < MI; ++mi)
#pragma unroll
        for (int ni = 0; ni < 4; ++ni)
#pragma unroll
            for (int r = 0; r < 4; ++r) {
                const int row = m0 + wm*(MI*16) + mi*16 + fq*4 + r;
                const int col = n0 + wn*64 + ni*16 + fm;
                float v = acc[mi][ni][r];
                if constexpr (HAS_RES) v += Res[(size_t)row*N + col];
                storeF(&C[(size_t)row*N + col], v);
            }
}

// ---------------------------------------------------------------------------
// Transpose + convert expert W0/W1: src fp32 [D][ED] (32 mats) -> bf16 [ED][D]
// Vectorized: float4 loads, bf16x8 stores.
// ---------------------------------------------------------------------------
__global__ __launch_bounds__(256) void transpose_kernel(
    const float* __restrict__ src, bf16* __restrict__ dst)
{
    __shared__ bf16 tile[64][65];   // tile[d][h] = W[d0+d][h0+h]
    const int h0 = blockIdx.x*64, d0 = blockIdx.y*64, m = blockIdx.z;
    const float* s = src + (size_t)m*D_*ED_;
    bf16*        o = dst + (size_t)m*ED_*D_;
    const int tid = threadIdx.x;
    const int r4 = tid >> 4, c4 = (tid & 15)*4;
#pragma unroll
    for (int i = 0; i < 4; ++i) {
        const int r = i*16 + r4;
        const float4 f = *(const float4*)&s[(size_t)(d0 + r)*ED_ + h0 + c4];
        tile[r][c4+0] = __float2bfloat16(f.x);
        tile[r][c4+1] = __float2bfloat16(f.y);
        tile[r][c4+2] = __float2bfloat16(f.z);
        tile[r][c4+3] = __float2bfloat16(f.w);
    }
    __syncthreads();
    const int hh8 = tid >> 3, cg = tid & 7;
#pragma unroll
    for (int j = 0; j < 2; ++j) {
        const int hh = j*32 + hh8;   // output row (h), 0..63
        short t8[8];
#pragma unroll
        for (int e = 0; e < 8; ++e) t8[e] = *(short*)&tile[cg*8 + e][hh];
        *(bf16x8*)&o[(size_t)(h0 + hh)*D_ + d0 + cg*8] = *(bf16x8*)t8;
    }
}

// ---------------------------------------------------------------------------
// MFMA expert mid, 3-buffer counted-vmcnt pipeline
// ---------------------------------------------------------------------------
__global__ __launch_bounds__(256) void expert_mid_mfma_kernel(
    const bf16* __restrict__ xffn, const bf16* __restrict__ w0t,
    const int* __restrict__ counts, const int* __restrict__ pairs,
    const float* __restrict__ pw, bf16* __restrict__ gbuf)
{
    const int ht = blockIdx.x, pt = blockIdx.y, e = blockIdx.z;
    const int cnt = counts[e];
    if (pt*128 >= cnt) return;
    __shared__ short Xs[3][128*32];   // 24 KB
    __shared__ short W0s[3][64*32];   // 12 KB
    __shared__ short W1s[3][64*32];   // 12 KB
    __shared__ int   toks[128];
    __shared__ float wrow[128];
    const int tid = threadIdx.x;
    const int w = tid >> 6, l = tid & 63;
    const int wm = w >> 1, wn = w & 1;
    const int lr = l >> 2, lq = l & 3;
    const int fm = l & 15, fq = l >> 4;
    if (tid < 128) {
        const int p = pt*128 + tid;
        if (p < cnt) { toks[tid] = pairs[e*CAP_ + p] >> 1; wrow[tid] = pw[e*CAP_ + p]; }
        else         { toks[tid] = 0;                      wrow[tid] = 0.f; }
    }
    __syncthreads();
    const int t0 = toks[w*16 + lr], t1 = toks[64 + w*16 + lr];
    const bf16* gx0 = xffn + (size_t)t0*D_ + lq*8;
    const bf16* gx1 = xffn + (size_t)t1*D_ + lq*8;
    const bf16* g0  = w0t + ((size_t)e*ED_ + ht*64 + w*16 + lr)*D_ + lq*8;
    const bf16* g1  = w0t + ((size_t)(16 + e)*ED_ + ht*64 + w*16 + lr)*D_ + lq*8;
    f32x4 acc1[4][2], acc2[4][2];
#pragma unroll
    for (int i = 0; i < 4; ++i)
#pragma unroll
        for (int j = 0; j < 2; ++j) {
            acc1[i][j] = (f32x4){0.f,0.f,0.f,0.f};
            acc2[i][j] = (f32x4){0.f,0.f,0.f,0.f};
        }
    auto stage = [&](int buf, int k0) {
        load16(gx0 + k0, &Xs[buf][(w*16)*32]);
        load16(gx1 + k0, &Xs[buf][(64 + w*16)*32]);
        load16(g0 + k0,  &W0s[buf][(w*16)*32]);
        load16(g1 + k0,  &W1s[buf][(w*16)*32]);
    };
    const int nk = D_ >> 5;
    stage(0, 0);
    stage(1, 32);
    int cur = 0;
    for (int t = 0; t < nk; ++t) {
        if (t + 1 < nk) pipe_wait_vm4(); else pipe_wait_vm0();
        if (t + 2 < nk) {
            const int stg = (cur + 2 >= 3) ? cur - 1 : cur + 2;
            stage(stg, (t + 2) << 5);
        }
        bf16x8 af[4], b0[2], b1[2];
#pragma unroll
        for (int mi = 0; mi < 4; ++mi)
            af[mi] = *(const bf16x8*)&Xs[cur][(wm*64 + mi*16 + fm)*32 + fq*8];
#pragma unroll
        for (int ni = 0; ni < 2; ++ni) {
            b0[ni] = *(const bf16x8*)&W0s[cur][(wn*32 + ni*16 + fm)*32 + fq*8];
            b1[ni] = *(const bf16x8*)&W1s[cur][(wn*32 + ni*16 + fm)*32 + fq*8];
        }
#pragma unroll
        for (int mi = 0; mi < 4; ++mi)
#pragma unroll
            for (int ni = 0; ni < 2; ++ni) {
                acc1[mi][ni] = MFMA16(af[mi], b0[ni], acc1[mi][ni]);
                acc2[mi][ni] = MFMA16(af[mi], b1[ni], acc2[mi][ni]);
            }
        cur = (cur == 2) ? 0 : cur + 1;
    }
#pragma unroll
    for (int mi = 0; mi < 4; ++mi)
#pragma unroll
        for (int ni = 0; ni < 2; ++ni)
#pragma unroll
            for (int r = 0; r < 4; ++r) {
                const int row = wm*64 + mi*16 + fq*4 + r;
                const int col = wn*32 + ni*16 + fm;
                const float h1 = acc1[mi][ni][r], h2 = acc2[mi][ni][r];
                const float g = wrow[row] * (h1 / (1.f + __expf(-h1))) * h2;
                gbuf[((size_t)e*CAP_ + pt*128 + row)*ED_ + ht*64 + col] = __float2bfloat16(g);
            }
}

// ---------------------------------------------------------------------------
// Shared-expert fused SwiGLU, 3-buffer counted-vmcnt pipeline:
// gsh[t][n] = silu(x@W1^T) * (x@W2^T), dense.
// ---------------------------------------------------------------------------
__global__ __launch_bounds__(256) void shared_swiglu_kernel(
    const bf16* __restrict__ xffn, const bf16* __restrict__ upbf,
    bf16* __restrict__ gsh)
{
    const int nt = blockIdx.x, mt = blockIdx.y;
    __shared__ short Xs[3][128*32];
    __shared__ short W0s[3][64*32];
    __shared__ short W1s[3][64*32];
    const int tid = threadIdx.x;
    const int w = tid >> 6, l = tid & 63;
    const int wm = w >> 1, wn = w & 1;
    const int lr = l >> 2, lq = l & 3;
    const int fm = l & 15, fq = l >> 4;
    const int m0 = mt*128, n0 = nt*64;
    const bf16* gx0 = xffn + (size_t)(m0 + w*16 + lr)*D_ + lq*8;
    const bf16* gx1 = xffn + (size_t)(m0 + 64 + w*16 + lr)*D_ + lq*8;
    const bf16* g0  = upbf + (size_t)(n0 + w*16 + lr)*D_ + lq*8;
    const bf16* g1  = upbf + (size_t)(DS_ + n0 + w*16 + lr)*D_ + lq*8;
    f32x4 acc1[4][2], acc2[4][2];
#pragma unroll
    for (int i = 0; i < 4; ++i)
#pragma unroll
        for (int j = 0; j < 2; ++j) {
            acc1[i][j] = (f32x4){0.f,0.f,0.f,0.f};
            acc2[i][j] = (f32x4){0.f,0.f,0.f,0.f};
        }
    auto stage = [&](int buf, int k0) {
        load16(gx0 + k0, &Xs[buf][(w*16)*32]);
        load16(gx1 + k0, &Xs[buf][(64 + w*16)*32]);
        load16(g0 + k0,  &W0s[buf][(w*16)*32]);
        load16(g1 + k0,  &W1s[buf][(w*16)*32]);
    };
    const int nk = D_ >> 5;
    stage(0, 0);
    stage(1, 32);
    int cur = 0;
    for (int t = 0; t < nk; ++t) {
        if (t + 1 < nk) pipe_wait_vm4(); else pipe_wait_vm0();
        if (t + 2 < nk) {
            const int stg = (cur + 2 >= 3) ? cur - 1 : cur + 2;
            stage(stg, (t + 2) << 5);
        }
        bf16x8 af[4], b0[2], b1[2];
#pragma unroll
        for (int mi = 0; mi < 4; ++mi)
            af[mi] = *(const bf16x8*)&Xs[cur][(wm*64 + mi*16 + fm)*32 + fq*8];
#pragma unroll
        for (int ni = 0; ni < 2; ++ni) {
            b0[ni] = *(const bf16x8*)&W0s[cur][(wn*32 + ni*16 + fm)*32 + fq*8];
            b1[ni] = *(const bf16x8*)&W1s[cur][(wn*32 + ni*16 + fm)*32 + fq*8];
        }
#pragma unroll
        for (int mi = 0; mi < 4; ++mi)
#pragma unroll
            for (int ni = 0; ni < 2; ++ni) {
                acc1[mi][ni] = MFMA16(af[mi], b0[ni], acc1[mi][ni]);
                acc2[mi][ni] = MFMA16(af[mi], b1[ni], acc2[mi][ni]);
            }
        cur = (cur == 2) ? 0 : cur + 1;
    }
#pragma unroll
    for (int mi = 0; mi < 4; ++mi)
#pragma unroll
        for (int ni = 0; ni < 2; ++ni)
#pragma unroll
            for (int r = 0; r < 4; ++r) {
                const int row = wm*64 + mi*16 + fq*4 + r;
                const int col = wn*32 + ni*16 + fm;
                const float h1 = acc1[mi][ni][r], h2 = acc2[mi][ni][r];
                const float g = (h1 / (1.f + __expf(-h1))) * h2;
                gsh[(size_t)(m0 + row)*DS_ + n0 + col] = __float2bfloat16(g);
            }
}

// ---------------------------------------------------------------------------
// MFMA expert down, 3-buffer counted-vmcnt pipeline
// ---------------------------------------------------------------------------
__global__ __launch_bounds__(256) void expert_down_mfma_kernel(
    const bf16* __restrict__ gbuf, const bf16* __restrict__ w2,
    const int* __restrict__ counts, const int* __restrict__ pairs,
    bf16* __restrict__ ytk)
{
    const int nt = blockIdx.x, pt = blockIdx.y, e = blockIdx.z;
    const int cnt = counts[e];
    if (pt*128 >= cnt) return;
    __shared__ short As[3][128*32];
    __shared__ short Bs[3][128*32];
    __shared__ int prs[128];
    const int tid = threadIdx.x;
    const int w = tid >> 6, l = tid & 63;
    const int wm = w >> 1, wn = w & 1;
    const int lr = l >> 2, lq = l & 3;
    const int fm = l & 15, fq = l >> 4;
    if (tid < 128) {
        const int p = pt*128 + tid;
        prs[tid] = (p < cnt) ? pairs[e*CAP_ + p] : -1;
    }
    __syncthreads();
    const bf16* ga = gbuf + ((size_t)e*CAP_ + pt*128 + w*16 + lr)*ED_ + lq*8;
    const bf16* gb = w2 + (size_t)e*D_*ED_ + (size_t)(nt*128 + w*16 + lr)*ED_ + lq*8;
    f32x4 acc[4][4];
#pragma unroll
    for (int i = 0; i < 4; ++i)
#pragma unroll
        for (int j = 0; j < 4; ++j) acc[i][j] = (f32x4){0.f,0.f,0.f,0.f};
    auto stage = [&](int buf, int k0) {
        load16(ga + k0,                  &As[buf][(w*16)*32]);
        load16(ga + k0 + (size_t)64*ED_, &As[buf][(64 + w*16)*32]);
        load16(gb + k0,                  &Bs[buf][(w*16)*32]);
        load16(gb + k0 + (size_t)64*ED_, &Bs[buf][(64 + w*16)*32]);
    };
    const int nk = ED_ >> 5;
    stage(0, 0);
    stage(1, 32);
    int cur = 0;
    for (int t = 0; t < nk; ++t) {
        if (t + 1 < nk) pipe_wait_vm4(); else pipe_wait_vm0();
        if (t + 2 < nk) {
            const int stg = (cur + 2 >= 3) ? cur - 1 : cur + 2;
            stage(stg, (t + 2) << 5);
        }
        bf16x8 af[4], bfr[4];
#pragma unroll
        for (int mi = 0; mi < 4; ++mi)
            af[mi] = *(const bf16x8*)&As[cur][(wm*64 + mi*16 + fm)*32 + fq*8];
#pragma unroll
        for (int ni = 0; ni < 4; ++ni)
            bfr[ni] = *(const bf16x8*)&Bs[cur][(wn*64 + ni*16 + fm)*32 + fq*8];
#pragma unroll
        for (int mi = 0; mi < 4; ++mi)
#pragma unroll
            for (int ni = 0; ni < 4; ++ni)
                acc[mi][ni] = MFMA16(af[mi], bfr[ni], acc[mi][ni]);
        cur = (cur == 2) ? 0 : cur + 1;
    }
#pragma unroll
    for (int mi = 0; mi < 4; ++mi)
#pragma unroll
        for (int r = 0; r < 4; ++r) {
            const int pr = prs[wm*64 + mi*16 + fq*4 + r];
            if (pr < 0) continue;
#pragma unroll
            for (int ni = 0; ni < 4; ++ni) {
                const int col = nt*128 + wn*64 + ni*16 + fm;
                ytk[(size_t)pr*D_ + col] = __float2bfloat16(acc[mi][ni][r]);
            }
        }
}

// ---------------------------------------------------------------------------
// RoPE: q PRE-SCALED by 0.125, written row-major [h][s][64].
// K written into swizzled 64x64 tiles: kswz[h][jt] tile of 4096 shorts,
// element (row=c=s&63, hd=d) stored at c*64 + (((d>>3) ^ (c&7))<<3) + (d&7).
// ---------------------------------------------------------------------------
__global__ __launch_bounds__(256) void rope_kernel(const bf16* __restrict__ qkv,
        bf16* __restrict__ qr, bf16* __restrict__ kswz)
{
    const int s = blockIdx.x, tid = threadIdx.x;
    const int c = s & 63, jt = s >> 6;
    for (int it = tid; it < 512; it += 256) {
        const int h = it >> 5, i = it & 31;
        const float inv = exp2f(-(float)i * 0.41524101186091903f);
        const float fr = (float)s * inv;
        float sn, cs;
        sincosf(fr, &sn, &cs);
        const size_t qb = (size_t)s*3072 + h*64 + i;
        const float q1 = __bfloat162float(qkv[qb]);
        const float q2 = __bfloat162float(qkv[qb + 32]);
        const size_t ob = ((size_t)h*S_ + s)*64 + i;
        qr[ob]      = __float2bfloat16(0.125f*( q1*cs + q2*sn));
        qr[ob + 32] = __float2bfloat16(0.125f*(-q1*sn + q2*cs));
        const float k1 = __bfloat162float(qkv[qb + 1024]);
        const float k2 = __bfloat162float(qkv[qb + 1024 + 32]);
        const size_t kb = ((size_t)(h*32 + jt))*4096 + (size_t)c*64;
        const int j0 = (i >> 3) ^ (c & 7);
        const int j1 = (4 + (i >> 3)) ^ (c & 7);
        kswz[kb + j0*8 + (i & 7)] = __float2bfloat16( k1*cs + k2*sn);
        kswz[kb + j1*8 + (i & 7)] = __float2bfloat16(-k1*sn + k2*cs);
    }
}

// ---------------------------------------------------------------------------
// V transpose: qkv V -> vswz[h][jt] swizzled 64x64 tile, row=hd, col=c.
// element (row=a, col=c) at a*64 + (((c>>3) ^ (a&7))<<3) + (c&7).
// ---------------------------------------------------------------------------
__global__ __launch_bounds__(256) void vtrans_kernel(
    const bf16* __restrict__ qkv, bf16* __restrict__ vswz)
{
    const int jt = blockIdx.x, h = blockIdx.y;
    __shared__ short Vt[64][72];
    const int tid = threadIdx.x;
#pragma unroll
    for (int it = 0; it < 2; ++it) {
        const int idx = it*256 + tid;
        const int cc = idx >> 3, seg = idx & 7;
        *(bf16x8*)&Vt[cc][seg*8] =
            *(const bf16x8*)(qkv + (size_t)(jt*64 + cc)*3072 + 2048 + h*64 + seg*8);
    }
    __syncthreads();
    bf16* out = vswz + ((size_t)(h*32 + jt))*4096;
#pragma unroll
    for (int it = 0; it < 2; ++it) {
        const int q = it*256 + tid;
        const int a = q >> 3, jo = q & 7;
        const int j = jo ^ (a & 7);
        short t8[8];
#pragma unroll
        for (int e = 0; e < 8; ++e) t8[e] = Vt[j*8 + e][a];
        *(bf16x8*)(out + a*64 + jo*8) = *(bf16x8*)t8;
    }
}

// ---------------------------------------------------------------------------
// MFMA flash attention, causal, load-balanced (unchanged).
// ---------------------------------------------------------------------------
__global__ __launch_bounds__(512) void attn_mfma_kernel(
    const bf16* __restrict__ qr, const bf16* __restrict__ kswz,
    const bf16* __restrict__ vswz, bf16* __restrict__ xattn)
{
    const int p = blockIdx.x, h = blockIdx.y;
    __shared__ short Ks[2][2][4096];   // [group][buf][tile]
    __shared__ short Vs[2][2][4096];
    __shared__ short Ps[2][64][72];    // [group][row][c], pitch 72
    __shared__ float Oc[64][64];       // group-1 partial O for combine
    __shared__ float Mc[64], Lc[64];   // group-1 partial m, l
    const int tid = threadIdx.x;
    const int w = tid >> 6, l = tid & 63;
    const int g = w >> 2, gw = w & 3;
    const int fm = l & 15, fq = l >> 4;
    const int sr = gw * 16;            // stripe row base within tile
    const bf16* ktile = kswz + (size_t)h*32*4096;
    const bf16* vtile = vswz + (size_t)h*32*4096;

    auto stageKV = [&](int jtile, int bufidx) {
        const bf16* ks_ = ktile + (size_t)jtile*4096 + gw*1024 + l*8;
        const bf16* vs_ = vtile + (size_t)jtile*4096 + gw*1024 + l*8;
        short* kd_ = &Ks[g][bufidx][gw*1024];
        short* vd_ = &Vs[g][bufidx][gw*1024];
        load16(ks_,       kd_);
        load16(ks_ + 512, kd_ + 512);
        load16(vs_,       vd_);
        load16(vs_ + 512, vd_ + 512);
    };

    for (int half = 0; half < 2; ++half) {
        const int qt = half ? (31 - p) : p;
        const bf16* gq = qr + ((size_t)h*S_ + qt*64 + sr + fm)*64 + fq*8;
        const bf16x8 aq0 = *(const bf16x8*)gq;
        const bf16x8 aq1 = *(const bf16x8*)(gq + 32);
        f32x4 Oa[4];
        float m_i[4], l_i[4];
#pragma unroll
        for (int i = 0; i < 4; ++i) {
            Oa[i] = (f32x4){0.f,0.f,0.f,0.f};
            m_i[i] = NEG_; l_i[i] = 0.f;
        }
        const int nj = qt + 1;
        const int itmax = (nj + 1) >> 1;
        if (g < nj) stageKV(g, 0);
        __syncthreads();
        for (int it = 0; it < itmax; ++it) {
            const int jt = g + 2*it;
            const int buf = it & 1;
            if (jt + 2 < nj) stageKV(jt + 2, buf ^ 1);
            if (jt < nj) {
                const short* kb = &Ks[g][buf][0];
                const short* vb = &Vs[g][buf][0];
                f32x4 sc[4];
#pragma unroll
                for (int ni = 0; ni < 4; ++ni) sc[ni] = (f32x4){0.f,0.f,0.f,0.f};
                __builtin_amdgcn_s_setprio(1);
#pragma unroll
                for (int ni = 0; ni < 4; ++ni) {
                    const int row = ni*16 + fm;
                    bf16x8 bk0 = *(const bf16x8*)&kb[row*64 + (( fq      ^ (fm & 7))<<3)];
                    bf16x8 bk1 = *(const bf16x8*)&kb[row*64 + (((fq + 4) ^ (fm & 7))<<3)];
                    sc[ni] = MFMA16(aq0, bk0, sc[ni]);
                    sc[ni] = MFMA16(aq1, bk1, sc[ni]);
                }
                __builtin_amdgcn_s_setprio(0);
                const bool diag = (jt == qt);
#pragma unroll
                for (int r = 0; r < 4; ++r) {
                    const int rowin = sr + fq*4 + r;
                    float rm = NEG_;
#pragma unroll
                    for (int ni = 0; ni < 4; ++ni) {
                        if (diag && (ni*16 + fm) > rowin) sc[ni][r] = NEG_;
                        rm = fmaxf(rm, sc[ni][r]);
                    }
                    rm = fmaxf(rm, __shfl_xor(rm, 1, 16));
                    rm = fmaxf(rm, __shfl_xor(rm, 2, 16));
                    rm = fmaxf(rm, __shfl_xor(rm, 4, 16));
                    rm = fmaxf(rm, __shfl_xor(rm, 8, 16));
                    const float mnew  = fmaxf(m_i[r], rm);
                    const float alpha = __expf(m_i[r] - mnew);
                    float rs = 0.f;
#pragma unroll
                    for (int ni = 0; ni < 4; ++ni) {
                        const float pv = __expf(sc[ni][r] - mnew);
                        sc[ni][r] = pv; rs += pv;
                    }
                    rs += __shfl_xor(rs, 1, 16);
                    rs += __shfl_xor(rs, 2, 16);
                    rs += __shfl_xor(rs, 4, 16);
                    rs += __shfl_xor(rs, 8, 16);
                    l_i[r] = l_i[r]*alpha + rs;
                    m_i[r] = mnew;
#pragma unroll
                    for (int ni = 0; ni < 4; ++ni) Oa[ni][r] *= alpha;
                }
#pragma unroll
                for (int ni = 0; ni < 4; ++ni)
#pragma unroll
                    for (int r = 0; r < 4; ++r)
                        Ps[g][sr + fq*4 + r][ni*16 + fm] = cvt1(sc[ni][r]);
                bf16x8 ap0 = *(const bf16x8*)&Ps[g][sr + fm][fq*8];
                bf16x8 ap1 = *(const bf16x8*)&Ps[g][sr + fm][32 + fq*8];
                __builtin_amdgcn_s_setprio(1);
#pragma unroll
                for (int ni = 0; ni < 4; ++ni) {
                    const int row = ni*16 + fm;
                    bf16x8 bv0 = *(const bf16x8*)&vb[row*64 + (( fq      ^ (fm & 7))<<3)];
                    bf16x8 bv1 = *(const bf16x8*)&vb[row*64 + (((fq + 4) ^ (fm & 7))<<3)];
                    Oa[ni] = MFMA16(ap0, bv0, Oa[ni]);
                    Oa[ni] = MFMA16(ap1, bv1, Oa[ni]);
                }
                __builtin_amdgcn_s_setprio(0);
            }
            __syncthreads();
        }
        if (g == 1) {
#pragma unroll
            for (int r = 0; r < 4; ++r) {
                const int row = sr + fq*4 + r;
                if (fm == 0) { Mc[row] = m_i[r]; Lc[row] = l_i[r]; }
#pragma unroll
                for (int ni = 0; ni < 4; ++ni) Oc[row][ni*16 + fm] = Oa[ni][r];
            }
        }
        __syncthreads();
        if (g == 0) {
#pragma unroll
            for (int r = 0; r < 4; ++r) {
                const int row = sr + fq*4 + r;
                const float m1 = Mc[row], l1 = Lc[row];
                const float mm = fmaxf(m_i[r], m1);
                const float a0 = __expf(m_i[r] - mm), a1 = __expf(m1 - mm);
                const float inv = 1.f / (l_i[r]*a0 + l1*a1);
                const int srow = qt*64 + row;
#pragma unroll
                for (int ni = 0; ni < 4; ++ni)
                    xattn[(size_t)srow*D_ + h*64 + ni*16 + fm] =
                        __float2bfloat16((Oa[ni][r]*a0 + Oc[row][ni*16 + fm]*a1)*inv);
            }
        }
        __syncthreads();
    }
}

// ---------------------------------------------------------------------------
// Router: one token per wave, 4 waves/block.
// ---------------------------------------------------------------------------
__global__ __launch_bounds__(256) void router_kernel(
    const bf16* __restrict__ xffn, const int* __restrict__ indices,
    const float* __restrict__ values, const float* __restrict__ mkT,
    const float* __restrict__ mbias, int* __restrict__ counts,
    int* __restrict__ pairs, float* __restrict__ pw)
{
    const int wv = threadIdx.x >> 6, lane = threadIdx.x & 63;
    const int t = blockIdx.x*4 + wv;
    const int i0 = indices[t*2], i1 = indices[t*2 + 1];
    const bf16* xp = xffn + (size_t)t*D_ + lane*16;
    const bf16x8 xa = *(const bf16x8*)xp;
    const bf16x8 xb = *(const bf16x8*)(xp + 8);
    float xv[16];
#pragma unroll
    for (int j = 0; j < 8; ++j) { xv[j] = b2f(xa[j]); xv[8 + j] = b2f(xb[j]); }
    const float* k0 = mkT + (size_t)i0*D_ + lane*16;
    const float* k1 = mkT + (size_t)i1*D_ + lane*16;
    float a0[16], a1[16];
#pragma unroll
    for (int j = 0; j < 4; ++j) {
        *(float4*)&a0[j*4] = *(const float4*)(k0 + j*4);
        *(float4*)&a1[j*4] = *(const float4*)(k1 + j*4);
    }
    float s0 = 0.f, s1 = 0.f;
#pragma unroll
    for (int j = 0; j < 16; ++j) {
        s0 = fmaf(xv[j], a0[j], s0);
        s1 = fmaf(xv[j], a1[j], s1);
    }
#pragma unroll
    for (int off = 32; off; off >>= 1) {
        s0 += __shfl_xor(s0, off, 64);
        s1 += __shfl_xor(s1, off, 64);
    }
    if (lane == 0) {
        const float v0 = values[t*2]     + s0 + mbias[i0];
        const float v1 = values[t*2 + 1] + s1 + mbias[i1];
        const float mx = fmaxf(v0, v1);
        const float e0 = __expf(v0 - mx), e1 = __expf(v1 - mx);
        const float inv = 1.f / (e0 + e1);
        const int p0 = atomicAdd(&counts[i0], 1);
        if (p0 < CAP_) { pairs[i0*CAP_ + p0] = t*2;     pw[i0*CAP_ + p0] = e0*inv; }
        const int p1 = atomicAdd(&counts[i1], 1);
        if (p1 < CAP_) { pairs[i1*CAP_ + p1] = t*2 + 1; pw[i1*CAP_ + p1] = e1*inv; }
    }
}

// ---------------------------------------------------------------------------
// Final: out = (ytk[2t]+ytk[2t+1])*coeff + rmsnorm(ysh)*shw + x_ffn_input
// ---------------------------------------------------------------------------
__global__ __launch_bounds__(256) void final_kernel(
    const bf16* __restrict__ ytk, const float* __restrict__ ysh,
    const float* __restrict__ xffin, const float* __restrict__ coeff,
    const float* __restrict__ shw, float* __restrict__ out)
{
    const int t = blockIdx.x, tid = threadIdx.x;
    __shared__ float red[4];
    const float4 yv = *(const float4*)(ysh + (size_t)t*D_ + tid*4);
    float ss = yv.x*yv.x + yv.y*yv.y + yv.z*yv.z + yv.w*yv.w;
#pragma unroll
    for (int off = 32; off; off >>= 1) ss += __shfl_xor(ss, off, 64);
    if ((tid & 63) == 0) red[tid >> 6] = ss;
    __syncthreads();
    const float rn = rsqrtf((red[0]+red[1]+red[2]+red[3]) * (1.f/D_) + 1e-5f);
    const int d = tid*4;
    const bf16x4 y0 = *(const bf16x4*)(ytk + (size_t)(t*2)*D_ + d);
    const bf16x4 y1 = *(const bf16x4*)(ytk + (size_t)(t*2 + 1)*D_ + d);
    const float4 cf = *(const float4*)(coeff + d);
    const float4 sw = *(const float4*)(shw + d);
    const float4 xf = *(const float4*)(xffin + (size_t)t*D_ + d);
    float4 o;
    o.x = (b2f(y0[0]) + b2f(y1[0]))*cf.x + yv.x*rn*sw.x + xf.x;
    o.y = (b2f(y0[1]) + b2f(y1[1]))*cf.y + yv.y*rn*sw.y + xf.y;
    o.z = (b2f(y0[2]) + b2f(y1[2]))*cf.z + yv.z*rn*sw.z + xf.z;
    o.w = (b2f(y0[3]) + b2f(y1[3]))*cf.w + yv.w*rn*sw.w + xf.w;
    *(float4*)(out + (size_t)t*D_ + d) = o;
}

// ---------------------------------------------------------------------------
extern "C" void kernel_launch(void* const* d_in, const int* in_sizes, int n_in,
                              void* d_out, int out_size, void* d_ws, size_t ws_size,
                              hipStream_t stream)
{
    const float* x_input     = (const float*)d_in[0];
    const int*   indices     = (const int*)  d_in[1];
    const float* values      = (const float*)d_in[2];
    const float* attn_w      = (const float*)d_in[3];
    const float* attn_o_w    = (const float*)d_in[4];
    const float* attn_norm_w = (const float*)d_in[5];
    const float* ffn_norm_w  = (const float*)d_in[6];
    const float* ffn_experts = (const float*)d_in[7];
    const float* main_keys   = (const float*)d_in[8];
    const float* main_bias   = (const float*)d_in[9];
    const float* out_coeff   = (const float*)d_in[10];
    const float* ffn_up_w    = (const float*)d_in[11];
    const float* ffn_down_w  = (const float*)d_in[12];
    const float* shared_nw   = (const float*)d_in[13];

    char* wp = (char*)d_ws;
    auto alloc = [&](size_t n) { char* p = wp; wp += (n + 255) & ~(size_t)255; return p; };
    // Region A (28 MB), time-multiplexed:
    //   phase 1: xn@0(4MB) | qkv@4(12MB) | qr@16(4MB) | xattn@20(4MB)
    //   phase 2 (after vtrans): w2bf@0(16MB)
    //   phase 3 (after o-proj): gsh@16(8MB)  (qr/xattn dead)
    char*  regA   = alloc(28*1024*1024 + 4096);
    bf16*  xn     = (bf16*)(regA);
    bf16*  qkv    = (bf16*)(regA + 4*1024*1024);
    bf16*  qr     = (bf16*)(regA + 16*1024*1024);
    bf16*  xattn  = (bf16*)(regA + 20*1024*1024);
    bf16*  w2bf   = (bf16*)(regA);                       // 16 MB, after vtrans
    bf16*  gsh    = (bf16*)(regA + 16*1024*1024);        //  8 MB, after o-proj
    float* xffin  = (float*)alloc((size_t)S_*D_*4);      //  8 MB
    // kswz/vswz alias xffin (dead until o-proj GEMM writes it, after attn)
    bf16*  kswz   = (bf16*)xffin;                        //  4 MB
    bf16*  vswz   = kswz + (size_t)H_*32*4096;           //  4 MB
    bf16*  xffn   = (bf16*) alloc((size_t)S_*D_*2);      //  4 MB
    int*   counts = (int*)  alloc(TE_*4);
    int*   pairs  = (int*)  alloc((size_t)TE_*CAP_*4);
    float* pwgt   = (float*)alloc((size_t)TE_*CAP_*4);
    float* mkT    = (float*)alloc((size_t)TE_*D_*4);     // 64 KB
    bf16*  gbuf   = (bf16*) alloc((size_t)TE_*CAP_*ED_*2);   // 8 MB
    bf16*  o_bf   = (bf16*)gbuf;                         // 2 MB, dead before expert_mid
    float* ysh    = (float*)((char*)gbuf);               // aliases gbuf (dead by then)
    bf16*  ytk    = (bf16*) alloc((size_t)S_*2*D_*2);        // 8 MB
    bf16*  awbf   = (bf16*)ytk;                          // 6 MB, dead before expert_down
    bf16*  w0t    = (bf16*) alloc((size_t)2*TE_*ED_*D_*2);   // 32 MB (W0^T, W1^T)
    bf16*  upbf   = (bf16*)w0t;                          // 8 MB, after expert_mid
    bf16*  dnbf   = (bf16*)((char*)w0t + 8*1024*1024);   // 4 MB, after expert_mid

    hipMemsetAsync(counts, 0, TE_*4, stream);

    // ---- front: only the small converts the attn chain needs.
    convert_kernel<<<(3*D_*D_)/2048, 256, 0, stream>>>(attn_w, awbf);
    convert_kernel<<<(D_*D_)/2048, 256, 0, stream>>>(attn_o_w, o_bf);
    mkT_kernel<<<(TE_*D_)/256, 256, 0, stream>>>(main_keys, mkT);

    // ---- attention block (compute-dense; coexists with harness fill) ----
    rmsnorm_kernel<<<S_, 256, 0, stream>>>(x_input, attn_norm_w, xn);
    gemm_mfma_bb_kernel<bf16,false,128><<<dim3(3*D_/128, S_/128), 256, 0, stream>>>(
        xn, awbf, qkv, nullptr, S_, 3*D_, D_);
    rope_kernel<<<S_, 256, 0, stream>>>(qkv, qr, kswz);
    vtrans_kernel<<<dim3(S_/64, H_), 256, 0, stream>>>(qkv, vswz);
    attn_mfma_kernel<<<dim3(16, H_), 512, 0, stream>>>(qr, kswz, vswz, xattn);

    // W0/W1 transpose+convert (deferred; needed by expert_mid)
    transpose_kernel<<<dim3(ED_/64, D_/64, 2*TE_), 256, 0, stream>>>(ffn_experts, w0t);

    gemm_mfma_bb_kernel<float,true,64><<<dim3(D_/64, S_/128), 256, 0, stream>>>(
        xattn, o_bf, xffin, x_input, S_, D_, D_);

    // ---- router + routed experts ----
    rmsnorm_kernel<<<S_, 256, 0, stream>>>(xffin, ffn_norm_w, xffn);
    router_kernel<<<S_/4, 256, 0, stream>>>(xffn, indices, values, mkT, main_bias,
                                            counts, pairs, pwgt);
    // qkv dead since vtrans -> convert W2 into region A (deferred)
    convert_kernel<<<(TE_*D_*ED_)/2048, 256, 0, stream>>>(
        ffn_experts + (size_t)2*TE_*D_*ED_, w2bf);
    expert_mid_mfma_kernel<<<dim3(ED_/64, CAP_/128, TE_), 256, 0, stream>>>(
        xffn, w0t, counts, pairs, pwgt, gbuf);
    // w0t dead -> convert shared-expert weights into it
    convert_kernel<<<(2*DS_*D_)/2048, 256, 0, stream>>>(ffn_up_w, upbf);
    convert_kernel<<<(D_*DS_)/2048, 256, 0, stream>>>(ffn_down_w, dnbf);

    // ---- shared expert fused SwiGLU (writes gsh directly; no u/silu pass) ----
    shared_swiglu_kernel<<<dim3(DS_/64, S_/128), 256, 0, stream>>>(xffn, upbf, gsh);

    expert_down_mfma_kernel<<<dim3(D_/128, CAP_/128, TE_), 256, 0, stream>>>(
        gbuf, w2bf, counts, pairs, ytk);

    // ---- shared expert down (w2bf dead after expert_down; ysh aliases gbuf) ----
    gemm_mfma_bb_kernel<float,false,64><<<dim3(D_/64, S_/128), 256, 0, stream>>>(
        gsh, dnbf, ysh, nullptr, S_, D_, DS_);

    // ---- combine ----
    final_kernel<<<S_, 256, 0, stream>>>(ytk, ysh, xffin, out_coeff, shared_nw,
                                         (float*)d_out);
}

// Round 9
// 481.053 us; speedup vs baseline: 1.0228x; 1.0228x over previous
//
#include <hip/hip_runtime.h>
#include <hip/hip_bf16.h>

using bf16 = __hip_bfloat16;

#define S_   2048
#define D_   1024
#define H_   16
#define HD_  64
#define TE_  16
#define ED_  512
#define DS_  2048
#define CAP_ 512

#define NEG_ -1e30f

typedef __attribute__((ext_vector_type(8))) short bf16x8;
typedef __attribute__((ext_vector_type(4))) short bf16x4;
typedef __attribute__((ext_vector_type(4))) float f32x4;
#define MFMA16(a, b, c) __builtin_amdgcn_mfma_f32_16x16x32_bf16(a, b, c, 0, 0, 0)

__device__ __forceinline__ void storeF(float* p, float v) { *p = v; }
__device__ __forceinline__ void storeF(bf16* p, float v)  { *p = __float2bfloat16(v); }
__device__ __forceinline__ short cvt1(float f) {
    bf16 h = __float2bfloat16(f);
    return *(short*)&h;
}
__device__ __forceinline__ float b2f(short s) {
    return __uint_as_float(((unsigned)(unsigned short)s) << 16);
}

// async global->LDS, 16B per lane; LDS dest = wave-uniform base + lane*16
__device__ __forceinline__ void load16(const bf16* g, short* l) {
    __builtin_amdgcn_global_load_lds(
        (const __attribute__((address_space(1))) unsigned*)g,
        (__attribute__((address_space(3))) unsigned*)l, 16, 0, 0);
}

// ---------------------------------------------------------------------------
// fp32 -> bf16 convert (vectorized, 8 elems/thread). n must be multiple of 2048.
// ---------------------------------------------------------------------------
__global__ __launch_bounds__(256) void convert_kernel(
        const float* __restrict__ src, bf16* __restrict__ dst)
{
    const size_t i = ((size_t)blockIdx.x*256 + threadIdx.x)*8;
    const float4 f0 = *(const float4*)(src + i);
    const float4 f1 = *(const float4*)(src + i + 4);
    short t8[8];
    t8[0]=cvt1(f0.x); t8[1]=cvt1(f0.y); t8[2]=cvt1(f0.z); t8[3]=cvt1(f0.w);
    t8[4]=cvt1(f1.x); t8[5]=cvt1(f1.y); t8[6]=cvt1(f1.z); t8[7]=cvt1(f1.w);
    *(bf16x8*)(dst + i) = *(bf16x8*)t8;
}

// ---------------------------------------------------------------------------
// main_keys transpose: [D][TE] fp32 -> [TE][D] fp32 (tiny, 64 KB)
// ---------------------------------------------------------------------------
__global__ __launch_bounds__(256) void mkT_kernel(
        const float* __restrict__ mk, float* __restrict__ mkT)
{
    const int idx = blockIdx.x*256 + threadIdx.x;   // 0..16383
    const int e = idx >> 10, d = idx & 1023;
    mkT[idx] = mk[d*TE_ + e];
}

// ---------------------------------------------------------------------------
// RMSNorm: fp32 in -> bf16 out (float4 loads, 4 elems/thread)
// ---------------------------------------------------------------------------
__global__ __launch_bounds__(256) void rmsnorm_kernel(
        const float* __restrict__ x, const float* __restrict__ w,
        bf16* __restrict__ out)
{
    const int t = blockIdx.x, tid = threadIdx.x;
    __shared__ float red[4];
    const float4 xv = *(const float4*)(x + (size_t)t*D_ + tid*4);
    float ss = xv.x*xv.x + xv.y*xv.y + xv.z*xv.z + xv.w*xv.w;
#pragma unroll
    for (int off = 32; off; off >>= 1) ss += __shfl_xor(ss, off, 64);
    if ((tid & 63) == 0) red[tid >> 6] = ss;
    __syncthreads();
    const float rn = rsqrtf((red[0]+red[1]+red[2]+red[3]) * (1.f/D_) + 1e-5f);
    const float4 wv = *(const float4*)(w + tid*4);
    short o[4];
    o[0] = cvt1(xv.x*rn*wv.x); o[1] = cvt1(xv.y*rn*wv.y);
    o[2] = cvt1(xv.z*rn*wv.z); o[3] = cvt1(xv.w*rn*wv.w);
    *(bf16x4*)(out + (size_t)t*D_ + tid*4) = *(bf16x4*)o;
}

// ---------------------------------------------------------------------------
// MFMA GEMM, both sides bf16, double-buffered LDS, BK=64 K-steps stored as
// two stacked 32-col halves ([buf][half][...]; 64B row stride -> no new bank
// conflicts). 32 MFMA/wave per barrier (2x the BK=32 version) -> half the
// vmcnt(0)+barrier drains per unit K. XCD-swizzled block order.
// BN = 128 (2x2 waves) or BN = 64 (4x1 waves). K must be a multiple of 64.
// C[M,N] = A[M,K](bf16) @ B[N,K]^T(bf16)
// ---------------------------------------------------------------------------
template<typename OutT, bool HAS_RES, int BN>
__global__ __launch_bounds__(256) void gemm_mfma_bb_kernel(
    const bf16* __restrict__ A, const bf16* __restrict__ B,
    OutT* __restrict__ C, const float* __restrict__ Res,
    int M, int N, int K)
{
    constexpr int MI = (BN == 128) ? 4 : 2;     // M fragments per wave
    __shared__ short As[2][2][128*32];          // [buf][half][...] 32 KB
    __shared__ short Bs[2][2][BN*32];           // 32 KB (BN=128) / 16 KB
    const int tid = threadIdx.x;
    const int w = tid >> 6, l = tid & 63;
    const int wm = (BN == 128) ? (w >> 1) : w;
    const int wn = (BN == 128) ? (w & 1) : 0;
    // bijective XCD swizzle over flattened grid (nwg % 8 == 0 for all launches)
    const int nwg = gridDim.x * gridDim.y;
    const int bid = blockIdx.y * gridDim.x + blockIdx.x;
    const int swz = ((nwg & 7) == 0) ? ((bid & 7) * (nwg >> 3) + (bid >> 3)) : bid;
    const int bx = swz % gridDim.x, by = swz / gridDim.x;
    const int m0 = by * 128, n0 = bx * BN;
    const int lr = l >> 2, lq = l & 3;
    const int fm = l & 15, fq = l >> 4;
    f32x4 acc[MI][4];
#pragma unroll
    for (int i = 0; i < MI; ++i)
#pragma unroll
        for (int j = 0; j < 4; ++j) acc[i][j] = (f32x4){0.f,0.f,0.f,0.f};

    const bf16* ga = A + (size_t)(m0 + w*16 + lr)*K + lq*8;
    const bf16* gb = B + (size_t)(n0 + w*16 + lr)*K + lq*8;

    auto stage = [&](int buf, int k0) {
#pragma unroll
        for (int h = 0; h < 2; ++h) {
            const int kh = k0 + h*32;
            load16(ga + kh,                &As[buf][h][(w*16)*32]);
            load16(ga + kh + (size_t)64*K, &As[buf][h][(64 + w*16)*32]);
            load16(gb + kh,                &Bs[buf][h][(w*16)*32]);
            if constexpr (BN == 128)
                load16(gb + kh + (size_t)64*K, &Bs[buf][h][(64 + w*16)*32]);
        }
    };
    stage(0, 0);
    __syncthreads();
    const int nk = K >> 6;
    for (int t = 0; t < nk; ++t) {
        const int cur = t & 1;
        if (t + 1 < nk) stage(cur ^ 1, (t + 1) << 6);
#pragma unroll
        for (int kk = 0; kk < 2; ++kk) {
            bf16x8 af[MI], bfr[4];
#pragma unroll
            for (int mi = 0; mi < MI; ++mi)
                af[mi] = *(const bf16x8*)&As[cur][kk][(wm*(MI*16) + mi*16 + fm)*32 + fq*8];
#pragma unroll
            for (int ni = 0; ni < 4; ++ni)
                bfr[ni] = *(const bf16x8*)&Bs[cur][kk][(wn*64 + ni*16 + fm)*32 + fq*8];
#pragma unroll
            for (int mi = 0; mi < MI; ++mi)
#pragma unroll
                for (int ni = 0; ni < 4; ++ni)
                    acc[mi][ni] = MFMA16(af[mi], bfr[ni], acc[mi][ni]);
        }
        __syncthreads();   // drains prefetch (vmcnt0) + orders buf reuse
    }
#pragma unroll
    for (int mi = 0; mi < MI; ++mi)
#pragma unroll
        for (int ni = 0; ni < 4; ++ni)
#pragma unroll
            for (int r = 0; r < 4; ++r) {
                const int row = m0 + wm*(MI*16) + mi*16 + fq*4 + r;
                const int col = n0 + wn*64 + ni*16 + fm;
                float v = acc[mi][ni][r];
                if constexpr (HAS_RES) v += Res[(size_t)row*N + col];
                storeF(&C[(size_t)row*N + col], v);
            }
}

// ---------------------------------------------------------------------------
// Transpose + convert expert W0/W1: src fp32 [D][ED] (32 mats) -> bf16 [ED][D]
// Vectorized: float4 loads, bf16x8 stores.
// ---------------------------------------------------------------------------
__global__ __launch_bounds__(256) void transpose_kernel(
    const float* __restrict__ src, bf16* __restrict__ dst)
{
    __shared__ bf16 tile[64][65];   // tile[d][h] = W[d0+d][h0+h]
    const int h0 = blockIdx.x*64, d0 = blockIdx.y*64, m = blockIdx.z;
    const float* s = src + (size_t)m*D_*ED_;
    bf16*        o = dst + (size_t)m*ED_*D_;
    const int tid = threadIdx.x;
    const int r4 = tid >> 4, c4 = (tid & 15)*4;
#pragma unroll
    for (int i = 0; i < 4; ++i) {
        const int r = i*16 + r4;
        const float4 f = *(const float4*)&s[(size_t)(d0 + r)*ED_ + h0 + c4];
        tile[r][c4+0] = __float2bfloat16(f.x);
        tile[r][c4+1] = __float2bfloat16(f.y);
        tile[r][c4+2] = __float2bfloat16(f.z);
        tile[r][c4+3] = __float2bfloat16(f.w);
    }
    __syncthreads();
    const int hh8 = tid >> 3, cg = tid & 7;
#pragma unroll
    for (int j = 0; j < 2; ++j) {
        const int hh = j*32 + hh8;   // output row (h), 0..63
        short t8[8];
#pragma unroll
        for (int e = 0; e < 8; ++e) t8[e] = *(short*)&tile[cg*8 + e][hh];
        *(bf16x8*)&o[(size_t)(h0 + hh)*D_ + d0 + cg*8] = *(bf16x8*)t8;
    }
}

// ---------------------------------------------------------------------------
// MFMA expert mid, BK=64 stacked halves, double-buffered
// ---------------------------------------------------------------------------
__global__ __launch_bounds__(256) void expert_mid_mfma_kernel(
    const bf16* __restrict__ xffn, const bf16* __restrict__ w0t,
    const int* __restrict__ counts, const int* __restrict__ pairs,
    const float* __restrict__ pw, bf16* __restrict__ gbuf)
{
    const int ht = blockIdx.x, pt = blockIdx.y, e = blockIdx.z;
    const int cnt = counts[e];
    if (pt*128 >= cnt) return;
    __shared__ short Xs[2][2][128*32];   // 32 KB
    __shared__ short W0s[2][2][64*32];   // 16 KB
    __shared__ short W1s[2][2][64*32];   // 16 KB
    __shared__ int   toks[128];
    __shared__ float wrow[128];
    const int tid = threadIdx.x;
    const int w = tid >> 6, l = tid & 63;
    const int wm = w >> 1, wn = w & 1;
    const int lr = l >> 2, lq = l & 3;
    const int fm = l & 15, fq = l >> 4;
    if (tid < 128) {
        const int p = pt*128 + tid;
        if (p < cnt) { toks[tid] = pairs[e*CAP_ + p] >> 1; wrow[tid] = pw[e*CAP_ + p]; }
        else         { toks[tid] = 0;                      wrow[tid] = 0.f; }
    }
    __syncthreads();
    const int t0 = toks[w*16 + lr], t1 = toks[64 + w*16 + lr];
    const bf16* gx0 = xffn + (size_t)t0*D_ + lq*8;
    const bf16* gx1 = xffn + (size_t)t1*D_ + lq*8;
    const bf16* g0  = w0t + ((size_t)e*ED_ + ht*64 + w*16 + lr)*D_ + lq*8;
    const bf16* g1  = w0t + ((size_t)(16 + e)*ED_ + ht*64 + w*16 + lr)*D_ + lq*8;
    f32x4 acc1[4][2], acc2[4][2];
#pragma unroll
    for (int i = 0; i < 4; ++i)
#pragma unroll
        for (int j = 0; j < 2; ++j) {
            acc1[i][j] = (f32x4){0.f,0.f,0.f,0.f};
            acc2[i][j] = (f32x4){0.f,0.f,0.f,0.f};
        }
    auto stage = [&](int buf, int k0) {
#pragma unroll
        for (int h = 0; h < 2; ++h) {
            const int kh = k0 + h*32;
            load16(gx0 + kh, &Xs[buf][h][(w*16)*32]);
            load16(gx1 + kh, &Xs[buf][h][(64 + w*16)*32]);
            load16(g0 + kh,  &W0s[buf][h][(w*16)*32]);
            load16(g1 + kh,  &W1s[buf][h][(w*16)*32]);
        }
    };
    stage(0, 0);
    __syncthreads();
    const int nk = D_ >> 6;
    for (int t = 0; t < nk; ++t) {
        const int cur = t & 1;
        if (t + 1 < nk) stage(cur ^ 1, (t + 1) << 6);
#pragma unroll
        for (int kk = 0; kk < 2; ++kk) {
            bf16x8 af[4], b0[2], b1[2];
#pragma unroll
            for (int mi = 0; mi < 4; ++mi)
                af[mi] = *(const bf16x8*)&Xs[cur][kk][(wm*64 + mi*16 + fm)*32 + fq*8];
#pragma unroll
            for (int ni = 0; ni < 2; ++ni) {
                b0[ni] = *(const bf16x8*)&W0s[cur][kk][(wn*32 + ni*16 + fm)*32 + fq*8];
                b1[ni] = *(const bf16x8*)&W1s[cur][kk][(wn*32 + ni*16 + fm)*32 + fq*8];
            }
#pragma unroll
            for (int mi = 0; mi < 4; ++mi)
#pragma unroll
                for (int ni = 0; ni < 2; ++ni) {
                    acc1[mi][ni] = MFMA16(af[mi], b0[ni], acc1[mi][ni]);
                    acc2[mi][ni] = MFMA16(af[mi], b1[ni], acc2[mi][ni]);
                }
        }
        __syncthreads();
    }
#pragma unroll
    for (int mi = 0; mi < 4; ++mi)
#pragma unroll
        for (int ni = 0; ni < 2; ++ni)
#pragma unroll
            for (int r = 0; r < 4; ++r) {
                const int row = wm*64 + mi*16 + fq*4 + r;
                const int col = wn*32 + ni*16 + fm;
                const float h1 = acc1[mi][ni][r], h2 = acc2[mi][ni][r];
                const float g = wrow[row] * (h1 / (1.f + __expf(-h1))) * h2;
                gbuf[((size_t)e*CAP_ + pt*128 + row)*ED_ + ht*64 + col] = __float2bfloat16(g);
            }
}

// ---------------------------------------------------------------------------
// Shared-expert fused SwiGLU, BK=64 stacked halves:
// gsh[t][n] = silu(x@W1^T) * (x@W2^T), dense.
// ---------------------------------------------------------------------------
__global__ __launch_bounds__(256) void shared_swiglu_kernel(
    const bf16* __restrict__ xffn, const bf16* __restrict__ upbf,
    bf16* __restrict__ gsh)
{
    const int nt = blockIdx.x, mt = blockIdx.y;
    __shared__ short Xs[2][2][128*32];
    __shared__ short W0s[2][2][64*32];
    __shared__ short W1s[2][2][64*32];
    const int tid = threadIdx.x;
    const int w = tid >> 6, l = tid & 63;
    const int wm = w >> 1, wn = w & 1;
    const int lr = l >> 2, lq = l & 3;
    const int fm = l & 15, fq = l >> 4;
    const int m0 = mt*128, n0 = nt*64;
    const bf16* gx0 = xffn + (size_t)(m0 + w*16 + lr)*D_ + lq*8;
    const bf16* gx1 = xffn + (size_t)(m0 + 64 + w*16 + lr)*D_ + lq*8;
    const bf16* g0  = upbf + (size_t)(n0 + w*16 + lr)*D_ + lq*8;
    const bf16* g1  = upbf + (size_t)(DS_ + n0 + w*16 + lr)*D_ + lq*8;
    f32x4 acc1[4][2], acc2[4][2];
#pragma unroll
    for (int i = 0; i < 4; ++i)
#pragma unroll
        for (int j = 0; j < 2; ++j) {
            acc1[i][j] = (f32x4){0.f,0.f,0.f,0.f};
            acc2[i][j] = (f32x4){0.f,0.f,0.f,0.f};
        }
    auto stage = [&](int buf, int k0) {
#pragma unroll
        for (int h = 0; h < 2; ++h) {
            const int kh = k0 + h*32;
            load16(gx0 + kh, &Xs[buf][h][(w*16)*32]);
            load16(gx1 + kh, &Xs[buf][h][(64 + w*16)*32]);
            load16(g0 + kh,  &W0s[buf][h][(w*16)*32]);
            load16(g1 + kh,  &W1s[buf][h][(w*16)*32]);
        }
    };
    stage(0, 0);
    __syncthreads();
    const int nk = D_ >> 6;
    for (int t = 0; t < nk; ++t) {
        const int cur = t & 1;
        if (t + 1 < nk) stage(cur ^ 1, (t + 1) << 6);
#pragma unroll
        for (int kk = 0; kk < 2; ++kk) {
            bf16x8 af[4], b0[2], b1[2];
#pragma unroll
            for (int mi = 0; mi < 4; ++mi)
                af[mi] = *(const bf16x8*)&Xs[cur][kk][(wm*64 + mi*16 + fm)*32 + fq*8];
#pragma unroll
            for (int ni = 0; ni < 2; ++ni) {
                b0[ni] = *(const bf16x8*)&W0s[cur][kk][(wn*32 + ni*16 + fm)*32 + fq*8];
                b1[ni] = *(const bf16x8*)&W1s[cur][kk][(wn*32 + ni*16 + fm)*32 + fq*8];
            }
#pragma unroll
            for (int mi = 0; mi < 4; ++mi)
#pragma unroll
                for (int ni = 0; ni < 2; ++ni) {
                    acc1[mi][ni] = MFMA16(af[mi], b0[ni], acc1[mi][ni]);
                    acc2[mi][ni] = MFMA16(af[mi], b1[ni], acc2[mi][ni]);
                }
        }
        __syncthreads();
    }
#pragma unroll
    for (int mi = 0; mi < 4; ++mi)
#pragma unroll
        for (int ni = 0; ni < 2; ++ni)
#pragma unroll
            for (int r = 0; r < 4; ++r) {
                const int row = wm*64 + mi*16 + fq*4 + r;
                const int col = wn*32 + ni*16 + fm;
                const float h1 = acc1[mi][ni][r], h2 = acc2[mi][ni][r];
                const float g = (h1 / (1.f + __expf(-h1))) * h2;
                gsh[(size_t)(m0 + row)*DS_ + n0 + col] = __float2bfloat16(g);
            }
}

// ---------------------------------------------------------------------------
// MFMA expert down, BK=64 stacked halves, double-buffered
// ---------------------------------------------------------------------------
__global__ __launch_bounds__(256) void expert_down_mfma_kernel(
    const bf16* __restrict__ gbuf, const bf16* __restrict__ w2,
    const int* __restrict__ counts, const int* __restrict__ pairs,
    bf16* __restrict__ ytk)
{
    const int nt = blockIdx.x, pt = blockIdx.y, e = blockIdx.z;
    const int cnt = counts[e];
    if (pt*128 >= cnt) return;
    __shared__ short As[2][2][128*32];
    __shared__ short Bs[2][2][128*32];
    __shared__ int prs[128];
    const int tid = threadIdx.x;
    const int w = tid >> 6, l = tid & 63;
    const int wm = w >> 1, wn = w & 1;
    const int lr = l >> 2, lq = l & 3;
    const int fm = l & 15, fq = l >> 4;
    if (tid < 128) {
        const int p = pt*128 + tid;
        prs[tid] = (p < cnt) ? pairs[e*CAP_ + p] : -1;
    }
    __syncthreads();
    const bf16* ga = gbuf + ((size_t)e*CAP_ + pt*128 + w*16 + lr)*ED_ + lq*8;
    const bf16* gb = w2 + (size_t)e*D_*ED_ + (size_t)(nt*128 + w*16 + lr)*ED_ + lq*8;
    f32x4 acc[4][4];
#pragma unroll
    for (int i = 0; i < 4; ++i)
#pragma unroll
        for (int j = 0; j < 4; ++j) acc[i][j] = (f32x4){0.f,0.f,0.f,0.f};
    auto stage = [&](int buf, int k0) {
#pragma unroll
        for (int h = 0; h < 2; ++h) {
            const int kh = k0 + h*32;
            load16(ga + kh,                  &As[buf][h][(w*16)*32]);
            load16(ga + kh + (size_t)64*ED_, &As[buf][h][(64 + w*16)*32]);
            load16(gb + kh,                  &Bs[buf][h][(w*16)*32]);
            load16(gb + kh + (size_t)64*ED_, &Bs[buf][h][(64 + w*16)*32]);
        }
    };
    stage(0, 0);
    __syncthreads();
    const int nk = ED_ >> 6;
    for (int t = 0; t < nk; ++t) {
        const int cur = t & 1;
        if (t + 1 < nk) stage(cur ^ 1, (t + 1) << 6);
#pragma unroll
        for (int kk = 0; kk < 2; ++kk) {
            bf16x8 af[4], bfr[4];
#pragma unroll
            for (int mi = 0; mi < 4; ++mi)
                af[mi] = *(const bf16x8*)&As[cur][kk][(wm*64 + mi*16 + fm)*32 + fq*8];
#pragma unroll
            for (int ni = 0; ni < 4; ++ni)
                bfr[ni] = *(const bf16x8*)&Bs[cur][kk][(wn*64 + ni*16 + fm)*32 + fq*8];
#pragma unroll
            for (int mi = 0; mi < 4; ++mi)
#pragma unroll
                for (int ni = 0; ni < 4; ++ni)
                    acc[mi][ni] = MFMA16(af[mi], bfr[ni], acc[mi][ni]);
        }
        __syncthreads();
    }
#pragma unroll
    for (int mi = 0; mi < 4; ++mi)
#pragma unroll
        for (int r = 0; r < 4; ++r) {
            const int pr = prs[wm*64 + mi*16 + fq*4 + r];
            if (pr < 0) continue;
#pragma unroll
            for (int ni = 0; ni < 4; ++ni) {
                const int col = nt*128 + wn*64 + ni*16 + fm;
                ytk[(size_t)pr*D_ + col] = __float2bfloat16(acc[mi][ni][r]);
            }
        }
}

// ---------------------------------------------------------------------------
// RoPE: q PRE-SCALED by 0.125, written row-major [h][s][64].
// K written into swizzled 64x64 tiles: kswz[h][jt] tile of 4096 shorts,
// element (row=c=s&63, hd=d) stored at c*64 + (((d>>3) ^ (c&7))<<3) + (d&7).
// ---------------------------------------------------------------------------
__global__ __launch_bounds__(256) void rope_kernel(const bf16* __restrict__ qkv,
        bf16* __restrict__ qr, bf16* __restrict__ kswz)
{
    const int s = blockIdx.x, tid = threadIdx.x;
    const int c = s & 63, jt = s >> 6;
    for (int it = tid; it < 512; it += 256) {
        const int h = it >> 5, i = it & 31;
        const float inv = exp2f(-(float)i * 0.41524101186091903f);
        const float fr = (float)s * inv;
        float sn, cs;
        sincosf(fr, &sn, &cs);
        const size_t qb = (size_t)s*3072 + h*64 + i;
        const float q1 = __bfloat162float(qkv[qb]);
        const float q2 = __bfloat162float(qkv[qb + 32]);
        const size_t ob = ((size_t)h*S_ + s)*64 + i;
        qr[ob]      = __float2bfloat16(0.125f*( q1*cs + q2*sn));
        qr[ob + 32] = __float2bfloat16(0.125f*(-q1*sn + q2*cs));
        const float k1 = __bfloat162float(qkv[qb + 1024]);
        const float k2 = __bfloat162float(qkv[qb + 1024 + 32]);
        const size_t kb = ((size_t)(h*32 + jt))*4096 + (size_t)c*64;
        const int j0 = (i >> 3) ^ (c & 7);
        const int j1 = (4 + (i >> 3)) ^ (c & 7);
        kswz[kb + j0*8 + (i & 7)] = __float2bfloat16( k1*cs + k2*sn);
        kswz[kb + j1*8 + (i & 7)] = __float2bfloat16(-k1*sn + k2*cs);
    }
}

// ---------------------------------------------------------------------------
// V transpose: qkv V -> vswz[h][jt] swizzled 64x64 tile, row=hd, col=c.
// element (row=a, col=c) at a*64 + (((c>>3) ^ (a&7))<<3) + (c&7).
// ---------------------------------------------------------------------------
__global__ __launch_bounds__(256) void vtrans_kernel(
    const bf16* __restrict__ qkv, bf16* __restrict__ vswz)
{
    const int jt = blockIdx.x, h = blockIdx.y;
    __shared__ short Vt[64][72];
    const int tid = threadIdx.x;
#pragma unroll
    for (int it = 0; it < 2; ++it) {
        const int idx = it*256 + tid;
        const int cc = idx >> 3, seg = idx & 7;
        *(bf16x8*)&Vt[cc][seg*8] =
            *(const bf16x8*)(qkv + (size_t)(jt*64 + cc)*3072 + 2048 + h*64 + seg*8);
    }
    __syncthreads();
    bf16* out = vswz + ((size_t)(h*32 + jt))*4096;
#pragma unroll
    for (int it = 0; it < 2; ++it) {
        const int q = it*256 + tid;
        const int a = q >> 3, jo = q & 7;
        const int j = jo ^ (a & 7);
        short t8[8];
#pragma unroll
        for (int e = 0; e < 8; ++e) t8[e] = Vt[j*8 + e][a];
        *(bf16x8*)(out + a*64 + jo*8) = *(bf16x8*)t8;
    }
}

// ---------------------------------------------------------------------------
// MFMA flash attention, causal, load-balanced (unchanged).
// ---------------------------------------------------------------------------
__global__ __launch_bounds__(512) void attn_mfma_kernel(
    const bf16* __restrict__ qr, const bf16* __restrict__ kswz,
    const bf16* __restrict__ vswz, bf16* __restrict__ xattn)
{
    const int p = blockIdx.x, h = blockIdx.y;
    __shared__ short Ks[2][2][4096];   // [group][buf][tile]
    __shared__ short Vs[2][2][4096];
    __shared__ short Ps[2][64][72];    // [group][row][c], pitch 72
    __shared__ float Oc[64][64];       // group-1 partial O for combine
    __shared__ float Mc[64], Lc[64];   // group-1 partial m, l
    const int tid = threadIdx.x;
    const int w = tid >> 6, l = tid & 63;
    const int g = w >> 2, gw = w & 3;
    const int fm = l & 15, fq = l >> 4;
    const int sr = gw * 16;            // stripe row base within tile
    const bf16* ktile = kswz + (size_t)h*32*4096;
    const bf16* vtile = vswz + (size_t)h*32*4096;

    auto stageKV = [&](int jtile, int bufidx) {
        const bf16* ks_ = ktile + (size_t)jtile*4096 + gw*1024 + l*8;
        const bf16* vs_ = vtile + (size_t)jtile*4096 + gw*1024 + l*8;
        short* kd_ = &Ks[g][bufidx][gw*1024];
        short* vd_ = &Vs[g][bufidx][gw*1024];
        load16(ks_,       kd_);
        load16(ks_ + 512, kd_ + 512);
        load16(vs_,       vd_);
        load16(vs_ + 512, vd_ + 512);
    };

    for (int half = 0; half < 2; ++half) {
        const int qt = half ? (31 - p) : p;
        const bf16* gq = qr + ((size_t)h*S_ + qt*64 + sr + fm)*64 + fq*8;
        const bf16x8 aq0 = *(const bf16x8*)gq;
        const bf16x8 aq1 = *(const bf16x8*)(gq + 32);
        f32x4 Oa[4];
        float m_i[4], l_i[4];
#pragma unroll
        for (int i = 0; i < 4; ++i) {
            Oa[i] = (f32x4){0.f,0.f,0.f,0.f};
            m_i[i] = NEG_; l_i[i] = 0.f;
        }
        const int nj = qt + 1;
        const int itmax = (nj + 1) >> 1;
        if (g < nj) stageKV(g, 0);
        __syncthreads();
        for (int it = 0; it < itmax; ++it) {
            const int jt = g + 2*it;
            const int buf = it & 1;
            if (jt + 2 < nj) stageKV(jt + 2, buf ^ 1);
            if (jt < nj) {
                const short* kb = &Ks[g][buf][0];
                const short* vb = &Vs[g][buf][0];
                f32x4 sc[4];
#pragma unroll
                for (int ni = 0; ni < 4; ++ni) sc[ni] = (f32x4){0.f,0.f,0.f,0.f};
                __builtin_amdgcn_s_setprio(1);
#pragma unroll
                for (int ni = 0; ni < 4; ++ni) {
                    const int row = ni*16 + fm;
                    bf16x8 bk0 = *(const bf16x8*)&kb[row*64 + (( fq      ^ (fm & 7))<<3)];
                    bf16x8 bk1 = *(const bf16x8*)&kb[row*64 + (((fq + 4) ^ (fm & 7))<<3)];
                    sc[ni] = MFMA16(aq0, bk0, sc[ni]);
                    sc[ni] = MFMA16(aq1, bk1, sc[ni]);
                }
                __builtin_amdgcn_s_setprio(0);
                const bool diag = (jt == qt);
#pragma unroll
                for (int r = 0; r < 4; ++r) {
                    const int rowin = sr + fq*4 + r;
                    float rm = NEG_;
#pragma unroll
                    for (int ni = 0; ni < 4; ++ni) {
                        if (diag && (ni*16 + fm) > rowin) sc[ni][r] = NEG_;
                        rm = fmaxf(rm, sc[ni][r]);
                    }
                    rm = fmaxf(rm, __shfl_xor(rm, 1, 16));
                    rm = fmaxf(rm, __shfl_xor(rm, 2, 16));
                    rm = fmaxf(rm, __shfl_xor(rm, 4, 16));
                    rm = fmaxf(rm, __shfl_xor(rm, 8, 16));
                    const float mnew  = fmaxf(m_i[r], rm);
                    const float alpha = __expf(m_i[r] - mnew);
                    float rs = 0.f;
#pragma unroll
                    for (int ni = 0; ni < 4; ++ni) {
                        const float pv = __expf(sc[ni][r] - mnew);
                        sc[ni][r] = pv; rs += pv;
                    }
                    rs += __shfl_xor(rs, 1, 16);
                    rs += __shfl_xor(rs, 2, 16);
                    rs += __shfl_xor(rs, 4, 16);
                    rs += __shfl_xor(rs, 8, 16);
                    l_i[r] = l_i[r]*alpha + rs;
                    m_i[r] = mnew;
#pragma unroll
                    for (int ni = 0; ni < 4; ++ni) Oa[ni][r] *= alpha;
                }
#pragma unroll
                for (int ni = 0; ni < 4; ++ni)
#pragma unroll
                    for (int r = 0; r < 4; ++r)
                        Ps[g][sr + fq*4 + r][ni*16 + fm] = cvt1(sc[ni][r]);
                bf16x8 ap0 = *(const bf16x8*)&Ps[g][sr + fm][fq*8];
                bf16x8 ap1 = *(const bf16x8*)&Ps[g][sr + fm][32 + fq*8];
                __builtin_amdgcn_s_setprio(1);
#pragma unroll
                for (int ni = 0; ni < 4; ++ni) {
                    const int row = ni*16 + fm;
                    bf16x8 bv0 = *(const bf16x8*)&vb[row*64 + (( fq      ^ (fm & 7))<<3)];
                    bf16x8 bv1 = *(const bf16x8*)&vb[row*64 + (((fq + 4) ^ (fm & 7))<<3)];
                    Oa[ni] = MFMA16(ap0, bv0, Oa[ni]);
                    Oa[ni] = MFMA16(ap1, bv1, Oa[ni]);
                }
                __builtin_amdgcn_s_setprio(0);
            }
            __syncthreads();
        }
        if (g == 1) {
#pragma unroll
            for (int r = 0; r < 4; ++r) {
                const int row = sr + fq*4 + r;
                if (fm == 0) { Mc[row] = m_i[r]; Lc[row] = l_i[r]; }
#pragma unroll
                for (int ni = 0; ni < 4; ++ni) Oc[row][ni*16 + fm] = Oa[ni][r];
            }
        }
        __syncthreads();
        if (g == 0) {
#pragma unroll
            for (int r = 0; r < 4; ++r) {
                const int row = sr + fq*4 + r;
                const float m1 = Mc[row], l1 = Lc[row];
                const float mm = fmaxf(m_i[r], m1);
                const float a0 = __expf(m_i[r] - mm), a1 = __expf(m1 - mm);
                const float inv = 1.f / (l_i[r]*a0 + l1*a1);
                const int srow = qt*64 + row;
#pragma unroll
                for (int ni = 0; ni < 4; ++ni)
                    xattn[(size_t)srow*D_ + h*64 + ni*16 + fm] =
                        __float2bfloat16((Oa[ni][r]*a0 + Oc[row][ni*16 + fm]*a1)*inv);
            }
        }
        __syncthreads();
    }
}

// ---------------------------------------------------------------------------
// Router: one token per wave, 4 waves/block.
// ---------------------------------------------------------------------------
__global__ __launch_bounds__(256) void router_kernel(
    const bf16* __restrict__ xffn, const int* __restrict__ indices,
    const float* __restrict__ values, const float* __restrict__ mkT,
    const float* __restrict__ mbias, int* __restrict__ counts,
    int* __restrict__ pairs, float* __restrict__ pw)
{
    const int wv = threadIdx.x >> 6, lane = threadIdx.x & 63;
    const int t = blockIdx.x*4 + wv;
    const int i0 = indices[t*2], i1 = indices[t*2 + 1];
    const bf16* xp = xffn + (size_t)t*D_ + lane*16;
    const bf16x8 xa = *(const bf16x8*)xp;
    const bf16x8 xb = *(const bf16x8*)(xp + 8);
    float xv[16];
#pragma unroll
    for (int j = 0; j < 8; ++j) { xv[j] = b2f(xa[j]); xv[8 + j] = b2f(xb[j]); }
    const float* k0 = mkT + (size_t)i0*D_ + lane*16;
    const float* k1 = mkT + (size_t)i1*D_ + lane*16;
    float a0[16], a1[16];
#pragma unroll
    for (int j = 0; j < 4; ++j) {
        *(float4*)&a0[j*4] = *(const float4*)(k0 + j*4);
        *(float4*)&a1[j*4] = *(const float4*)(k1 + j*4);
    }
    float s0 = 0.f, s1 = 0.f;
#pragma unroll
    for (int j = 0; j < 16; ++j) {
        s0 = fmaf(xv[j], a0[j], s0);
        s1 = fmaf(xv[j], a1[j], s1);
    }
#pragma unroll
    for (int off = 32; off; off >>= 1) {
        s0 += __shfl_xor(s0, off, 64);
        s1 += __shfl_xor(s1, off, 64);
    }
    if (lane == 0) {
        const float v0 = values[t*2]     + s0 + mbias[i0];
        const float v1 = values[t*2 + 1] + s1 + mbias[i1];
        const float mx = fmaxf(v0, v1);
        const float e0 = __expf(v0 - mx), e1 = __expf(v1 - mx);
        const float inv = 1.f / (e0 + e1);
        const int p0 = atomicAdd(&counts[i0], 1);
        if (p0 < CAP_) { pairs[i0*CAP_ + p0] = t*2;     pw[i0*CAP_ + p0] = e0*inv; }
        const int p1 = atomicAdd(&counts[i1], 1);
        if (p1 < CAP_) { pairs[i1*CAP_ + p1] = t*2 + 1; pw[i1*CAP_ + p1] = e1*inv; }
    }
}

// ---------------------------------------------------------------------------
// Final: out = (ytk[2t]+ytk[2t+1])*coeff + rmsnorm(ysh)*shw + x_ffn_input
// ---------------------------------------------------------------------------
__global__ __launch_bounds__(256) void final_kernel(
    const bf16* __restrict__ ytk, const float* __restrict__ ysh,
    const float* __restrict__ xffin, const float* __restrict__ coeff,
    const float* __restrict__ shw, float* __restrict__ out)
{
    const int t = blockIdx.x, tid = threadIdx.x;
    __shared__ float red[4];
    const float4 yv = *(const float4*)(ysh + (size_t)t*D_ + tid*4);
    float ss = yv.x*yv.x + yv.y*yv.y + yv.z*yv.z + yv.w*yv.w;
#pragma unroll
    for (int off = 32; off; off >>= 1) ss += __shfl_xor(ss, off, 64);
    if ((tid & 63) == 0) red[tid >> 6] = ss;
    __syncthreads();
    const float rn = rsqrtf((red[0]+red[1]+red[2]+red[3]) * (1.f/D_) + 1e-5f);
    const int d = tid*4;
    const bf16x4 y0 = *(const bf16x4*)(ytk + (size_t)(t*2)*D_ + d);
    const bf16x4 y1 = *(const bf16x4*)(ytk + (size_t)(t*2 + 1)*D_ + d);
    const float4 cf = *(const float4*)(coeff + d);
    const float4 sw = *(const float4*)(shw + d);
    const float4 xf = *(const float4*)(xffin + (size_t)t*D_ + d);
    float4 o;
    o.x = (b2f(y0[0]) + b2f(y1[0]))*cf.x + yv.x*rn*sw.x + xf.x;
    o.y = (b2f(y0[1]) + b2f(y1[1]))*cf.y + yv.y*rn*sw.y + xf.y;
    o.z = (b2f(y0[2]) + b2f(y1[2]))*cf.z + yv.z*rn*sw.z + xf.z;
    o.w = (b2f(y0[3]) + b2f(y1[3]))*cf.w + yv.w*rn*sw.w + xf.w;
    *(float4*)(out + (size_t)t*D_ + d) = o;
}

// ---------------------------------------------------------------------------
extern "C" void kernel_launch(void* const* d_in, const int* in_sizes, int n_in,
                              void* d_out, int out_size, void* d_ws, size_t ws_size,
                              hipStream_t stream)
{
    const float* x_input     = (const float*)d_in[0];
    const int*   indices     = (const int*)  d_in[1];
    const float* values      = (const float*)d_in[2];
    const float* attn_w      = (const float*)d_in[3];
    const float* attn_o_w    = (const float*)d_in[4];
    const float* attn_norm_w = (const float*)d_in[5];
    const float* ffn_norm_w  = (const float*)d_in[6];
    const float* ffn_experts = (const float*)d_in[7];
    const float* main_keys   = (const float*)d_in[8];
    const float* main_bias   = (const float*)d_in[9];
    const float* out_coeff   = (const float*)d_in[10];
    const float* ffn_up_w    = (const float*)d_in[11];
    const float* ffn_down_w  = (const float*)d_in[12];
    const float* shared_nw   = (const float*)d_in[13];

    char* wp = (char*)d_ws;
    auto alloc = [&](size_t n) { char* p = wp; wp += (n + 255) & ~(size_t)255; return p; };
    // Region A (28 MB), time-multiplexed:
    //   phase 1: xn@0(4MB) | qkv@4(12MB) | qr@16(4MB) | xattn@20(4MB)
    //   phase 2 (after vtrans): w2bf@0(16MB)
    //   phase 3 (after o-proj): gsh@16(8MB)  (qr/xattn dead)
    char*  regA   = alloc(28*1024*1024 + 4096);
    bf16*  xn     = (bf16*)(regA);
    bf16*  qkv    = (bf16*)(regA + 4*1024*1024);
    bf16*  qr     = (bf16*)(regA + 16*1024*1024);
    bf16*  xattn  = (bf16*)(regA + 20*1024*1024);
    bf16*  w2bf   = (bf16*)(regA);                       // 16 MB, after vtrans
    bf16*  gsh    = (bf16*)(regA + 16*1024*1024);        //  8 MB, after o-proj
    float* xffin  = (float*)alloc((size_t)S_*D_*4);      //  8 MB
    // kswz/vswz alias xffin (dead until o-proj GEMM writes it, after attn)
    bf16*  kswz   = (bf16*)xffin;                        //  4 MB
    bf16*  vswz   = kswz + (size_t)H_*32*4096;           //  4 MB
    bf16*  xffn   = (bf16*) alloc((size_t)S_*D_*2);      //  4 MB
    int*   counts = (int*)  alloc(TE_*4);
    int*   pairs  = (int*)  alloc((size_t)TE_*CAP_*4);
    float* pwgt   = (float*)alloc((size_t)TE_*CAP_*4);
    float* mkT    = (float*)alloc((size_t)TE_*D_*4);     // 64 KB
    bf16*  gbuf   = (bf16*) alloc((size_t)TE_*CAP_*ED_*2);   // 8 MB
    bf16*  o_bf   = (bf16*)gbuf;                         // 2 MB, dead before expert_mid
    float* ysh    = (float*)((char*)gbuf);               // aliases gbuf (dead by then)
    bf16*  ytk    = (bf16*) alloc((size_t)S_*2*D_*2);        // 8 MB
    bf16*  awbf   = (bf16*)ytk;                          // 6 MB, dead before expert_down
    bf16*  w0t    = (bf16*) alloc((size_t)2*TE_*ED_*D_*2);   // 32 MB (W0^T, W1^T)
    bf16*  upbf   = (bf16*)w0t;                          // 8 MB, after expert_mid
    bf16*  dnbf   = (bf16*)((char*)w0t + 8*1024*1024);   // 4 MB, after expert_mid

    hipMemsetAsync(counts, 0, TE_*4, stream);

    // ---- front: only the small converts the attn chain needs.
    convert_kernel<<<(3*D_*D_)/2048, 256, 0, stream>>>(attn_w, awbf);
    convert_kernel<<<(D_*D_)/2048, 256, 0, stream>>>(attn_o_w, o_bf);
    mkT_kernel<<<(TE_*D_)/256, 256, 0, stream>>>(main_keys, mkT);

    // ---- attention block (compute-dense; coexists with harness fill) ----
    rmsnorm_kernel<<<S_, 256, 0, stream>>>(x_input, attn_norm_w, xn);
    gemm_mfma_bb_kernel<bf16,false,128><<<dim3(3*D_/128, S_/128), 256, 0, stream>>>(
        xn, awbf, qkv, nullptr, S_, 3*D_, D_);
    rope_kernel<<<S_, 256, 0, stream>>>(qkv, qr, kswz);
    vtrans_kernel<<<dim3(S_/64, H_), 256, 0, stream>>>(qkv, vswz);
    attn_mfma_kernel<<<dim3(16, H_), 512, 0, stream>>>(qr, kswz, vswz, xattn);

    // W0/W1 transpose+convert (deferred; needed by expert_mid)
    transpose_kernel<<<dim3(ED_/64, D_/64, 2*TE_), 256, 0, stream>>>(ffn_experts, w0t);

    gemm_mfma_bb_kernel<float,true,64><<<dim3(D_/64, S_/128), 256, 0, stream>>>(
        xattn, o_bf, xffin, x_input, S_, D_, D_);

    // ---- router + routed experts ----
    rmsnorm_kernel<<<S_, 256, 0, stream>>>(xffin, ffn_norm_w, xffn);
    router_kernel<<<S_/4, 256, 0, stream>>>(xffn, indices, values, mkT, main_bias,
                                            counts, pairs, pwgt);
    // qkv dead since vtrans -> convert W2 into region A (deferred)
    convert_kernel<<<(TE_*D_*ED_)/2048, 256, 0, stream>>>(
        ffn_experts + (size_t)2*TE_*D_*ED_, w2bf);
    expert_mid_mfma_kernel<<<dim3(ED_/64, CAP_/128, TE_), 256, 0, stream>>>(
        xffn, w0t, counts, pairs, pwgt, gbuf);
    // w0t dead -> convert shared-expert weights into it
    convert_kernel<<<(2*DS_*D_)/2048, 256, 0, stream>>>(ffn_up_w, upbf);
    convert_kernel<<<(D_*DS_)/2048, 256, 0, stream>>>(ffn_down_w, dnbf);

    // ---- shared expert fused SwiGLU (writes gsh directly; no u/silu pass) ----
    shared_swiglu_kernel<<<dim3(DS_/64, S_/128), 256, 0, stream>>>(xffn, upbf, gsh);

    expert_down_mfma_kernel<<<dim3(D_/128, CAP_/128, TE_), 256, 0, stream>>>(
        gbuf, w2bf, counts, pairs, ytk);

    // ---- shared expert down (w2bf dead after expert_down; ysh aliases gbuf) ----
    gemm_mfma_bb_kernel<float,false,64><<<dim3(D_/64, S_/128), 256, 0, stream>>>(
        gsh, dnbf, ysh, nullptr, S_, D_, DS_);

    // ---- combine ----
    final_kernel<<<S_, 256, 0, stream>>>(ytk, ysh, xffin, out_coeff, shared_nw,
                                         (float*)d_out);
}